// Round 19
// baseline (409.911 us; speedup 1.0000x reference)
//
#include <hip/hip_runtime.h>

// ---------------------------------------------------------------------------
// ComplexHoloLinear: out[n,r] = sum_k x[n,k] * (Wr[r,k] + cos(phase[b])*Wi[r,k])
// b = n / SEQ.  Wr/Wi dense-assembled from COO (duplicates sum).
//
// Pipeline: memset(4KB) -> bin (256 scatter blocks, LDS bucket-sort, rows
// reg-cached || 4096 xconv blocks) -> assemble (1024 blocks, 64KB LDS,
// 2 row-half passes) -> gemm R19: TWO 32KB LDS bufs + launch_bounds(512,2)
// (VGPR ~120, no spill) -> 2 blocks/CU resource-driven occupancy; cross-
// block TLP hides HBM latency instead of R14's 3-deep prefetch.
// R17 lesson: (512,4) caps VGPR at 64 -> acc spills (15.5GB traffic, 10x).
// ---------------------------------------------------------------------------

#define K_IN   4096
#define F_OUT  4096
#define SEQ    2048
#define NROW   8192            // BATCH * SEQ
#define NNZ    4194304
#define WELEM  16777216        // F_OUT * K_IN
#define NBUCK  1024            // buckets of 4 rows
#define SEGB   5120            // slots/bucket; lambda=4096 -> 16 sigma

typedef float  f32x4  __attribute__((ext_vector_type(4)));
typedef __bf16 bf16x8 __attribute__((ext_vector_type(8)));
typedef unsigned short u16x8 __attribute__((ext_vector_type(8)));

__device__ __forceinline__ unsigned short f2bf(float f) {
  unsigned u = __builtin_bit_cast(unsigned, f);
  u += 0x7fffu + ((u >> 16) & 1u);          // round-to-nearest-even
  return (unsigned short)(u >> 16);
}
__device__ __forceinline__ float bf2f(unsigned short b) {
  return __builtin_bit_cast(float, (unsigned)b << 16);
}

// ---------------- 1. bucket-bin COO (LDS sort) + fused xconv --------------
// record = pk<<32 | bucket<<14 | rlow<<12 | col  (assemble masks &16383).
__global__ __launch_bounds__(1024) void bin_kernel(
    const int* __restrict__ rows, const int* __restrict__ cols,
    const float* __restrict__ wre, const float* __restrict__ wim,
    unsigned* __restrict__ cursor, unsigned long long* __restrict__ records,
    const float* __restrict__ x, unsigned short* __restrict__ Xb) {
  __shared__ unsigned long long sorted[16384];   // 128 KB
  __shared__ unsigned cnt[NBUCK];                // 4 KB (mutable cursor)
  __shared__ unsigned loff[NBUCK];               // 4 KB (pristine excl scan)
  __shared__ unsigned gbase[NBUCK];              // 4 KB (global claim base)
  const int b = blockIdx.x;
  if (b < 256) {
    const int tid = threadIdx.x;
    const int e0 = b << 14;                  // 16384 entries per block
    cnt[tid] = 0u;
    __syncthreads();
    int rcache[16];                          // rows cached in regs (pass2 reuse)
    #pragma unroll
    for (int i = 0; i < 16; ++i) {           // pass 1: count per bucket
      rcache[i] = rows[e0 + (i << 10) + tid];
      atomicAdd(&cnt[((unsigned)rcache[i]) >> 2], 1u);
    }
    __syncthreads();
    const unsigned c0 = cnt[tid];
    gbase[tid] = c0 ? atomicAdd(&cursor[tid], c0) : 0u;
    // inclusive scan of cnt into loff
    loff[tid] = c0;
    __syncthreads();
    #pragma unroll
    for (int d = 1; d < 1024; d <<= 1) {
      const unsigned v = loff[tid];
      const unsigned a = (tid >= d) ? loff[tid - d] : 0u;
      __syncthreads();
      loff[tid] = v + a;
      __syncthreads();
    }
    const unsigned excl = loff[tid] - c0;
    loff[tid] = excl;                        // pristine exclusive offset
    cnt[tid]  = excl;                        // running local cursor
    __syncthreads();
    for (int i = 0; i < 16; ++i) {           // pass 2: LDS bucket-sort
      const int e = e0 + (i << 10) + tid;
      const unsigned r  = (unsigned)rcache[i];
      const unsigned bk = r >> 2;
      const unsigned lr = atomicAdd(&cnt[bk], 1u);
      const unsigned pk = (unsigned)f2bf(wre[e]) | ((unsigned)f2bf(wim[e]) << 16);
      sorted[lr] = ((unsigned long long)pk << 32) |
                   ((unsigned long long)bk << 14) |
                   ((r & 3u) << 12) | (unsigned)cols[e];
    }
    __syncthreads();
    #pragma unroll
    for (int i = 0; i < 16; ++i) {           // streaming write, run-coalesced
      const int idx = (i << 10) + tid;
      const unsigned long long v = sorted[idx];
      const unsigned bk = (unsigned)(v >> 14) & 1023u;
      const unsigned dst = gbase[bk] + ((unsigned)idx - loff[bk]);
      if (dst < SEGB) records[(size_t)bk * SEGB + dst] = v;
    }
  } else {                                   // xconv: 4096 blocks x 8192 elems
    const size_t i8 = (((size_t)(b - 256) << 10) + threadIdx.x) << 3;
    f32x4 a = *(const f32x4*)(x + i8);
    f32x4 c = *(const f32x4*)(x + i8 + 4);
    u16x8 v;
    v[0] = f2bf(a[0]); v[1] = f2bf(a[1]); v[2] = f2bf(a[2]); v[3] = f2bf(a[3]);
    v[4] = f2bf(c[0]); v[5] = f2bf(c[1]); v[6] = f2bf(c[2]); v[7] = f2bf(c[3]);
    *(u16x8*)(Xb + i8) = v;
  }
}

// ---------------- 2. assemble bucket in 2 row-half passes + fold ----------
__global__ __launch_bounds__(1024) void assemble_kernel(
    const unsigned* __restrict__ cursor,
    const unsigned long long* __restrict__ records,
    const float* __restrict__ phase, unsigned short* __restrict__ Wb) {
  __shared__ float accRe[8192];              // 32 KB  (2 rows x 4096 cols)
  __shared__ float accIm[8192];              // 32 KB
  const int bk  = blockIdx.x;
  const int tid = threadIdx.x;
  unsigned cnt = cursor[bk];
  if (cnt > SEGB) cnt = SEGB;
  const unsigned long long* seg = records + (size_t)bk * SEGB;
  float cb[4];
  cb[0] = cosf(phase[0]); cb[1] = cosf(phase[1]);
  cb[2] = cosf(phase[2]); cb[3] = cosf(phase[3]);
  #pragma unroll
  for (int p = 0; p < 2; ++p) {              // row-half p: rows 2p, 2p+1
    #pragma unroll
    for (int i = 0; i < 8; ++i) {
      accRe[(i << 10) + tid] = 0.f;
      accIm[(i << 10) + tid] = 0.f;
    }
    __syncthreads();
    for (unsigned i = tid; i < cnt; i += 1024) {
      const unsigned long long rec = seg[i];
      const unsigned s = (unsigned)rec & 16383u;   // rlow*4096 + col
      if ((int)(s >> 13) == p) {
        const unsigned sh = s & 8191u;
        atomicAdd(&accRe[sh], bf2f((unsigned short)((rec >> 32) & 0xffffu)));
        atomicAdd(&accIm[sh], bf2f((unsigned short)(rec >> 48)));
      }
    }
    __syncthreads();
    #pragma unroll
    for (int it = 0; it < 8; ++it) {
      const int sh = (it << 10) + tid;
      const float re = accRe[sh];
      const float im = accIm[sh];
      const size_t off = ((size_t)bk << 14) + ((size_t)p << 13) + sh;
      #pragma unroll
      for (int bb = 0; bb < 4; ++bb)         // == row*4096 + col
        Wb[((size_t)bb << 24) + off] = f2bf(re + cb[bb] * im);
    }
    __syncthreads();                         // fold reads done before re-zero
  }
}

// ---------------- 3. bf16 GEMM: out = Xb @ Wb[batch]^T --------------------
// 256x256 tile, 512 thr (8 waves 2x4), 16x16x32 MFMA, BK=32.
// R19: TWO 32KB LDS bufs (64KB/block) + launch_bounds(512,2) -> VGPR ~120,
// LDS-driven 2 blocks/CU, 4 waves/SIMD. Per-iter {STAGE buf t+1 (4 gloads);
// vmcnt(4); barrier; 12 ds_read + 32 MFMA; lgkmcnt(0)+barrier}.
#define GLOAD_LDS(g, l)                                                        \
  __builtin_amdgcn_global_load_lds(                                            \
      (const __attribute__((address_space(1))) unsigned int*)(g),              \
      (__attribute__((address_space(3))) unsigned int*)(l), 16, 0, 0)

__global__ __launch_bounds__(512, 2) void gemm_kernel(
    const unsigned short* __restrict__ Xb,   // [8192][4096] bf16 bits
    const unsigned short* __restrict__ Wb,   // [4][4096][4096] bf16 bits
    float* __restrict__ out) {               // [8192][4096] f32
  __shared__ unsigned short lds[32768];      // 64KB: 2 bufs x [A|B][256][32]

  const int tid  = threadIdx.x;
  const int wid  = tid >> 6;                 // 0..7
  const int lane = tid & 63;
  const int wr   = wid >> 2;                 // wave row 0..1 (128 rows each)
  const int wc   = wid & 3;                  // wave col 0..3 (64 cols each)

  const int bid  = blockIdx.x;               // 0..511
  const int swz  = ((bid & 7) << 6) | (bid >> 3);  // xcd*64 + idx (512%8==0)
  const int brow = swz >> 4;                 // 0..31
  const int bcol = swz & 15;                 // 0..15
  const size_t M0 = (size_t)brow << 8;       // *256
  const int batch = brow >> 3;               // 2048 rows/batch / 256
  const unsigned short* Ap = Xb + M0 * K_IN;
  const unsigned short* Bp = Wb + ((size_t)batch << 24) + (((size_t)bcol << 8) * K_IN);

  // staging geometry: per round, wave covers 16 rows x 4 slots of 16B
  const int srow4 = lane >> 2;               // row within 16-row chunk
  const int gsl   = (((lane & 3) ^ ((lane >> 2) & 3) ^ ((lane >> 4) & 3)) << 3);
  // fragment geometry (16x16x32, K=32 = full buf)
  const int lrow = lane & 15;
  const int sb   = lane >> 4;                // k-slot 0..3
  const int fsl  = ((sb ^ (lrow & 3) ^ ((lrow >> 2) & 3)) << 3);

  f32x4 acc[8][4] = {};

#define STAGE(buf, kt)                                                         \
  {                                                                            \
    _Pragma("unroll")                                                          \
    for (int l = 0; l < 2; ++l) {                                              \
      const int rb = (l << 7) + (wid << 4);                                    \
      GLOAD_LDS(Ap + (size_t)(rb + srow4) * K_IN + (size_t)(((kt) << 5) + gsl),\
                &lds[((buf) << 14) + (rb << 5)]);                              \
    }                                                                          \
    _Pragma("unroll")                                                          \
    for (int l = 0; l < 2; ++l) {                                              \
      const int rb = (l << 7) + (wid << 4);                                    \
      GLOAD_LDS(Bp + (size_t)(rb + srow4) * K_IN + (size_t)(((kt) << 5) + gsl),\
                &lds[((buf) << 14) + 8192 + (rb << 5)]);                       \
    }                                                                          \
  }

#define COMPUTE(buf)                                                           \
  {                                                                            \
    const unsigned short* la = &lds[(buf) << 14];                              \
    const unsigned short* lb = la + 8192;                                      \
    bf16x8 af[8], bff[4];                                                      \
    _Pragma("unroll")                                                          \
    for (int m = 0; m < 8; ++m)                                                \
      af[m] = *(const bf16x8*)&la[(((wr << 7) + (m << 4) + lrow) << 5) + fsl]; \
    _Pragma("unroll")                                                          \
    for (int n = 0; n < 4; ++n)                                                \
      bff[n] = *(const bf16x8*)&lb[(((wc << 6) + (n << 4) + lrow) << 5) + fsl];\
    __builtin_amdgcn_s_setprio(1);                                             \
    _Pragma("unroll")                                                          \
    for (int m = 0; m < 8; ++m)                                                \
      _Pragma("unroll")                                                        \
      for (int n = 0; n < 4; ++n)                                              \
        acc[m][n] = __builtin_amdgcn_mfma_f32_16x16x32_bf16(                   \
            af[m], bff[n], acc[m][n], 0, 0, 0);                                \
    __builtin_amdgcn_s_setprio(0);                                             \
  }

#define STEP(cb, sbuf, kt)                                                     \
  {                                                                            \
    STAGE(sbuf, kt);                                                           \
    asm volatile("s_waitcnt vmcnt(4)\n\ts_barrier" ::: "memory");              \
    COMPUTE(cb);                                                               \
    asm volatile("s_waitcnt lgkmcnt(0)\n\ts_barrier" ::: "memory");            \
  }

  STAGE(0, 0);                               // prologue: K-step 0 -> buf0
  for (int I = 0; I < 63; ++I) {             // K-steps 0..125
    STEP(0, 1, 2 * I + 1);                   // stage k2I+1, compute k2I
    STEP(1, 0, 2 * I + 2);                   // stage k2I+2, compute k2I+1
  }
  STEP(0, 1, 127);                           // stage k127, compute k126
  asm volatile("s_waitcnt vmcnt(0)\n\ts_barrier" ::: "memory");
  COMPUTE(1);                                // k127

  // epilogue: C/D layout col = lane&15, row = (lane>>4)*4 + j  [m89/m91]
  const int ch = lane >> 4;
  float* op = out + (M0 + (size_t)(wr << 7)) * F_OUT + ((size_t)bcol << 8) + (wc << 6);
  #pragma unroll
  for (int m = 0; m < 8; ++m)
    #pragma unroll
    for (int n = 0; n < 4; ++n)
      #pragma unroll
      for (int j = 0; j < 4; ++j)
        op[(size_t)((m << 4) + (ch << 2) + j) * F_OUT + (n << 4) + lrow] = acc[m][n][j];
#undef STAGE
#undef COMPUTE
#undef STEP
}

// ---------------- fallback kernels (small ws) ------------------------------
__global__ __launch_bounds__(256) void scatter_kernel(
    const int* __restrict__ rows, const int* __restrict__ cols,
    const float* __restrict__ wre, const float* __restrict__ wim,
    unsigned short* __restrict__ Wcb) {
  int e = blockIdx.x * 256 + threadIdx.x;
  int r = rows[e];
  int c = cols[e];
  unsigned pk = (unsigned)f2bf(wre[e]) | ((unsigned)f2bf(wim[e]) << 16);
  size_t idx = ((size_t)r << 12) + (size_t)c;
  asm volatile("global_atomic_pk_add_bf16 %0, %1, off"
               :: "v"(Wcb + (idx << 1)), "v"(pk) : "memory");
}
__global__ __launch_bounds__(256) void fold_kernel(
    const unsigned short* __restrict__ Wcb, const float* __restrict__ phase,
    unsigned short* __restrict__ Wb) {
  size_t i8 = ((size_t)blockIdx.x * 256 + threadIdx.x) << 3;
  float cb[4];
  cb[0] = cosf(phase[0]); cb[1] = cosf(phase[1]);
  cb[2] = cosf(phase[2]); cb[3] = cosf(phase[3]);
  const unsigned short* p = Wcb + (i8 << 1);
  u16x8 a = *(const u16x8*)(p);
  u16x8 b = *(const u16x8*)(p + 8);
  float rr[8], ii[8];
  rr[0] = bf2f(a[0]); ii[0] = bf2f(a[1]);
  rr[1] = bf2f(a[2]); ii[1] = bf2f(a[3]);
  rr[2] = bf2f(a[4]); ii[2] = bf2f(a[5]);
  rr[3] = bf2f(a[6]); ii[3] = bf2f(a[7]);
  rr[4] = bf2f(b[0]); ii[4] = bf2f(b[1]);
  rr[5] = bf2f(b[2]); ii[5] = bf2f(b[3]);
  rr[6] = bf2f(b[4]); ii[6] = bf2f(b[5]);
  rr[7] = bf2f(b[6]); ii[7] = bf2f(b[7]);
  #pragma unroll
  for (int bb = 0; bb < 4; ++bb) {
    float c = cb[bb];
    u16x8 v;
    #pragma unroll
    for (int j = 0; j < 8; ++j) v[j] = f2bf(rr[j] + c * ii[j]);
    *(u16x8*)(Wb + ((size_t)bb << 24) + i8) = v;
  }
}
__global__ __launch_bounds__(256) void xconv_kernel(
    const float* __restrict__ x, unsigned short* __restrict__ Xb) {
  size_t i8 = ((size_t)blockIdx.x * 256 + threadIdx.x) << 3;
  f32x4 a = *(const f32x4*)(x + i8);
  f32x4 c = *(const f32x4*)(x + i8 + 4);
  u16x8 v;
  v[0] = f2bf(a[0]); v[1] = f2bf(a[1]); v[2] = f2bf(a[2]); v[3] = f2bf(a[3]);
  v[4] = f2bf(c[0]); v[5] = f2bf(c[1]); v[6] = f2bf(c[2]); v[7] = f2bf(c[3]);
  *(u16x8*)(Xb + i8) = v;
}
__global__ __launch_bounds__(256) void naive_kernel(
    const float* __restrict__ x, const unsigned short* __restrict__ Wcb,
    const float* __restrict__ phase, float* __restrict__ out) {
  int n = blockIdx.x >> 4;
  int r = ((blockIdx.x & 15) << 8) | threadIdx.x;
  float cb = cosf(phase[n >> 11]);
  const float* xp = x + ((size_t)n << 12);
  const unsigned short* wc = Wcb + (((size_t)r << 12) << 1);
  float ar = 0.f, ai = 0.f;
  for (int k = 0; k < K_IN; ++k) {
    float xv = xp[k];
    ar += xv * bf2f(wc[2 * k]);
    ai += xv * bf2f(wc[2 * k + 1]);
  }
  out[((size_t)n << 12) + r] = ar + cb * ai;
}

// ---------------------------------------------------------------------------
extern "C" void kernel_launch(void* const* d_in, const int* in_sizes, int n_in,
                              void* d_out, int out_size, void* d_ws, size_t ws_size,
                              hipStream_t stream) {
  const float* x     = (const float*)d_in[0];
  const int*   rows  = (const int*)d_in[1];
  const int*   cols  = (const int*)d_in[2];
  const float* wre   = (const float*)d_in[3];
  const float* wim   = (const float*)d_in[4];
  const float* phase = (const float*)d_in[5];
  float* out = (float*)d_out;

  const size_t WS_FULL = (size_t)268435456;  // 256MB
  const size_t WS_MAIN = (size_t)201326592;  // 192MB
  if (ws_size >= WS_FULL) {
    // Wb [0,128MB) | Xb [128,192MB) | records [192,~232MB) | cursor @240MB
    unsigned short*     Wb      = (unsigned short*)d_ws;
    unsigned short*     Xb      = (unsigned short*)((char*)d_ws + (size_t)134217728);
    unsigned long long* records = (unsigned long long*)((char*)d_ws + (size_t)201326592);
    unsigned*           cursor  = (unsigned*)((char*)d_ws + (size_t)251658240);
    hipMemsetAsync(cursor, 0, NBUCK * sizeof(unsigned), stream);
    bin_kernel<<<256 + 4096, 1024, 0, stream>>>(rows, cols, wre, wim,
                                                cursor, records, x, Xb);
    assemble_kernel<<<NBUCK, 1024, 0, stream>>>(cursor, records, phase, Wb);
    gemm_kernel<<<512, 512, 0, stream>>>(Xb, Wb, out);
  } else if (ws_size >= WS_MAIN) {
    unsigned short* Wcb = (unsigned short*)d_ws;
    unsigned short* Wb  = (unsigned short*)((char*)d_ws + (size_t)67108864);
    unsigned short* Xb  = (unsigned short*)d_ws;
    hipMemsetAsync(d_ws, 0, (size_t)WELEM * 4, stream);
    scatter_kernel<<<NNZ / 256, 256, 0, stream>>>(rows, cols, wre, wim, Wcb);
    fold_kernel<<<WELEM / 8 / 256, 256, 0, stream>>>(Wcb, phase, Wb);
    xconv_kernel<<<(size_t)NROW * K_IN / 8 / 256, 256, 0, stream>>>(x, Xb);
    gemm_kernel<<<512, 512, 0, stream>>>(Xb, Wb, out);
  } else {
    unsigned short* Wcb = (unsigned short*)d_ws;
    hipMemsetAsync(d_ws, 0, (size_t)WELEM * 4, stream);
    scatter_kernel<<<NNZ / 256, 256, 0, stream>>>(rows, cols, wre, wim, Wcb);
    naive_kernel<<<NROW * 16, 256, 0, stream>>>(x, Wcb, phase, out);
  }
}

// Round 20
// 403.452 us; speedup vs baseline: 1.0160x; 1.0160x over previous
//
#include <hip/hip_runtime.h>

// ---------------------------------------------------------------------------
// ComplexHoloLinear: out[n,r] = sum_k x[n,k] * (Wr[r,k] + cos(phase[b])*Wi[r,k])
// b = n / SEQ.  Wr/Wi dense-assembled from COO (duplicates sum).
//
// FINAL proven pipeline (R18, 401.7us):
//   memset(4KB) -> bin (256 scatter blocks: LDS bucket-sort, reg-cached rows
//   || 4096 xconv blocks) -> assemble (1024 blocks, 64KB LDS, 2 row-half
//   passes) -> gemm (256x256 tile, BK=32, FOUR 32KB LDS bufs, vmcnt(12)
//   3-iter-deep prefetch, lgkmcnt(0)-drained trailing barrier).
// Protected decisions (do not change without re-measuring):
//   - launch_bounds(512,2): (512,4) caps VGPR 64 -> acc spill, 10x (R17)
//   - 16x16x32 MFMA: 32x32x16 adds 2.5e7 LDS conflicts, no win (R11)
//   - 2-buffer/64KB variant: occupancy unchanged, loses prefetch depth (R19)
//   - phase-split schedules: 3 faithful attempts all regressed (R5/R6/R9)
// ---------------------------------------------------------------------------

#define K_IN   4096
#define F_OUT  4096
#define SEQ    2048
#define NROW   8192            // BATCH * SEQ
#define NNZ    4194304
#define WELEM  16777216        // F_OUT * K_IN
#define NBUCK  1024            // buckets of 4 rows
#define SEGB   5120            // slots/bucket; lambda=4096 -> 16 sigma

typedef float  f32x4  __attribute__((ext_vector_type(4)));
typedef __bf16 bf16x8 __attribute__((ext_vector_type(8)));
typedef unsigned short u16x8 __attribute__((ext_vector_type(8)));

__device__ __forceinline__ unsigned short f2bf(float f) {
  unsigned u = __builtin_bit_cast(unsigned, f);
  u += 0x7fffu + ((u >> 16) & 1u);          // round-to-nearest-even
  return (unsigned short)(u >> 16);
}
__device__ __forceinline__ float bf2f(unsigned short b) {
  return __builtin_bit_cast(float, (unsigned)b << 16);
}

// ---------------- 1. bucket-bin COO (LDS sort) + fused xconv --------------
// record = pk<<32 | bucket<<14 | rlow<<12 | col  (assemble masks &16383).
__global__ __launch_bounds__(1024) void bin_kernel(
    const int* __restrict__ rows, const int* __restrict__ cols,
    const float* __restrict__ wre, const float* __restrict__ wim,
    unsigned* __restrict__ cursor, unsigned long long* __restrict__ records,
    const float* __restrict__ x, unsigned short* __restrict__ Xb) {
  __shared__ unsigned long long sorted[16384];   // 128 KB
  __shared__ unsigned cnt[NBUCK];                // 4 KB (mutable cursor)
  __shared__ unsigned loff[NBUCK];               // 4 KB (pristine excl scan)
  __shared__ unsigned gbase[NBUCK];              // 4 KB (global claim base)
  const int b = blockIdx.x;
  if (b < 256) {
    const int tid = threadIdx.x;
    const int e0 = b << 14;                  // 16384 entries per block
    cnt[tid] = 0u;
    __syncthreads();
    int rcache[16];                          // rows cached in regs (pass2 reuse)
    #pragma unroll
    for (int i = 0; i < 16; ++i) {           // pass 1: count per bucket
      rcache[i] = rows[e0 + (i << 10) + tid];
      atomicAdd(&cnt[((unsigned)rcache[i]) >> 2], 1u);
    }
    __syncthreads();
    const unsigned c0 = cnt[tid];
    gbase[tid] = c0 ? atomicAdd(&cursor[tid], c0) : 0u;
    // inclusive scan of cnt into loff
    loff[tid] = c0;
    __syncthreads();
    #pragma unroll
    for (int d = 1; d < 1024; d <<= 1) {
      const unsigned v = loff[tid];
      const unsigned a = (tid >= d) ? loff[tid - d] : 0u;
      __syncthreads();
      loff[tid] = v + a;
      __syncthreads();
    }
    const unsigned excl = loff[tid] - c0;
    loff[tid] = excl;                        // pristine exclusive offset
    cnt[tid]  = excl;                        // running local cursor
    __syncthreads();
    for (int i = 0; i < 16; ++i) {           // pass 2: LDS bucket-sort
      const int e = e0 + (i << 10) + tid;
      const unsigned r  = (unsigned)rcache[i];
      const unsigned bk = r >> 2;
      const unsigned lr = atomicAdd(&cnt[bk], 1u);
      const unsigned pk = (unsigned)f2bf(wre[e]) | ((unsigned)f2bf(wim[e]) << 16);
      sorted[lr] = ((unsigned long long)pk << 32) |
                   ((unsigned long long)bk << 14) |
                   ((r & 3u) << 12) | (unsigned)cols[e];
    }
    __syncthreads();
    #pragma unroll
    for (int i = 0; i < 16; ++i) {           // streaming write, run-coalesced
      const int idx = (i << 10) + tid;
      const unsigned long long v = sorted[idx];
      const unsigned bk = (unsigned)(v >> 14) & 1023u;
      const unsigned dst = gbase[bk] + ((unsigned)idx - loff[bk]);
      if (dst < SEGB) records[(size_t)bk * SEGB + dst] = v;
    }
  } else {                                   // xconv: 4096 blocks x 8192 elems
    const size_t i8 = (((size_t)(b - 256) << 10) + threadIdx.x) << 3;
    f32x4 a = *(const f32x4*)(x + i8);
    f32x4 c = *(const f32x4*)(x + i8 + 4);
    u16x8 v;
    v[0] = f2bf(a[0]); v[1] = f2bf(a[1]); v[2] = f2bf(a[2]); v[3] = f2bf(a[3]);
    v[4] = f2bf(c[0]); v[5] = f2bf(c[1]); v[6] = f2bf(c[2]); v[7] = f2bf(c[3]);
    *(u16x8*)(Xb + i8) = v;
  }
}

// ---------------- 2. assemble bucket in 2 row-half passes + fold ----------
__global__ __launch_bounds__(1024) void assemble_kernel(
    const unsigned* __restrict__ cursor,
    const unsigned long long* __restrict__ records,
    const float* __restrict__ phase, unsigned short* __restrict__ Wb) {
  __shared__ float accRe[8192];              // 32 KB  (2 rows x 4096 cols)
  __shared__ float accIm[8192];              // 32 KB
  const int bk  = blockIdx.x;
  const int tid = threadIdx.x;
  unsigned cnt = cursor[bk];
  if (cnt > SEGB) cnt = SEGB;
  const unsigned long long* seg = records + (size_t)bk * SEGB;
  float cb[4];
  cb[0] = cosf(phase[0]); cb[1] = cosf(phase[1]);
  cb[2] = cosf(phase[2]); cb[3] = cosf(phase[3]);
  #pragma unroll
  for (int p = 0; p < 2; ++p) {              // row-half p: rows 2p, 2p+1
    #pragma unroll
    for (int i = 0; i < 8; ++i) {
      accRe[(i << 10) + tid] = 0.f;
      accIm[(i << 10) + tid] = 0.f;
    }
    __syncthreads();
    for (unsigned i = tid; i < cnt; i += 1024) {
      const unsigned long long rec = seg[i];
      const unsigned s = (unsigned)rec & 16383u;   // rlow*4096 + col
      if ((int)(s >> 13) == p) {
        const unsigned sh = s & 8191u;
        atomicAdd(&accRe[sh], bf2f((unsigned short)((rec >> 32) & 0xffffu)));
        atomicAdd(&accIm[sh], bf2f((unsigned short)(rec >> 48)));
      }
    }
    __syncthreads();
    #pragma unroll
    for (int it = 0; it < 8; ++it) {
      const int sh = (it << 10) + tid;
      const float re = accRe[sh];
      const float im = accIm[sh];
      const size_t off = ((size_t)bk << 14) + ((size_t)p << 13) + sh;
      #pragma unroll
      for (int bb = 0; bb < 4; ++bb)         // == row*4096 + col
        Wb[((size_t)bb << 24) + off] = f2bf(re + cb[bb] * im);
    }
    __syncthreads();                         // fold reads done before re-zero
  }
}

// ---------------- 3. bf16 GEMM: out = Xb @ Wb[batch]^T  (R14, frozen) -----
// 256x256 tile, 512 thr (8 waves 2x4), 16x16x32 MFMA, BK=32, FOUR 32KB LDS
// bufs: stage buf t+3 each iter; vmcnt(12) waits loads issued 3 iters
// (~1100cyc) earlier -> HBM latency hidden; lgkmcnt(0)+barrier trailing.
#define GLOAD_LDS(g, l)                                                        \
  __builtin_amdgcn_global_load_lds(                                            \
      (const __attribute__((address_space(1))) unsigned int*)(g),              \
      (__attribute__((address_space(3))) unsigned int*)(l), 16, 0, 0)

__global__ __launch_bounds__(512, 2) void gemm_kernel(
    const unsigned short* __restrict__ Xb,   // [8192][4096] bf16 bits
    const unsigned short* __restrict__ Wb,   // [4][4096][4096] bf16 bits
    float* __restrict__ out) {               // [8192][4096] f32
  __shared__ unsigned short lds[65536];      // 128KB: 4 bufs x [A|B][256][32]

  const int tid  = threadIdx.x;
  const int wid  = tid >> 6;                 // 0..7
  const int lane = tid & 63;
  const int wr   = wid >> 2;                 // wave row 0..1 (128 rows each)
  const int wc   = wid & 3;                  // wave col 0..3 (64 cols each)

  const int bid  = blockIdx.x;               // 0..511
  const int swz  = ((bid & 7) << 6) | (bid >> 3);  // xcd*64 + idx (512%8==0)
  const int brow = swz >> 4;                 // 0..31
  const int bcol = swz & 15;                 // 0..15
  const size_t M0 = (size_t)brow << 8;       // *256
  const int batch = brow >> 3;               // 2048 rows/batch / 256
  const unsigned short* Ap = Xb + M0 * K_IN;
  const unsigned short* Bp = Wb + ((size_t)batch << 24) + (((size_t)bcol << 8) * K_IN);

  // staging geometry: per round, wave covers 16 rows x 4 slots of 16B
  const int srow4 = lane >> 2;               // row within 16-row chunk
  const int gsl   = (((lane & 3) ^ ((lane >> 2) & 3) ^ ((lane >> 4) & 3)) << 3);
  // fragment geometry (16x16x32, K=32 = full buf)
  const int lrow = lane & 15;
  const int sb   = lane >> 4;                // k-slot 0..3
  const int fsl  = ((sb ^ (lrow & 3) ^ ((lrow >> 2) & 3)) << 3);

  f32x4 acc[8][4] = {};

#define STAGE(buf, kt)                                                         \
  {                                                                            \
    _Pragma("unroll")                                                          \
    for (int l = 0; l < 2; ++l) {                                              \
      const int rb = (l << 7) + (wid << 4);                                    \
      GLOAD_LDS(Ap + (size_t)(rb + srow4) * K_IN + (size_t)(((kt) << 5) + gsl),\
                &lds[((buf) << 14) + (rb << 5)]);                              \
    }                                                                          \
    _Pragma("unroll")                                                          \
    for (int l = 0; l < 2; ++l) {                                              \
      const int rb = (l << 7) + (wid << 4);                                    \
      GLOAD_LDS(Bp + (size_t)(rb + srow4) * K_IN + (size_t)(((kt) << 5) + gsl),\
                &lds[((buf) << 14) + 8192 + (rb << 5)]);                       \
    }                                                                          \
  }

#define COMPUTE(buf)                                                           \
  {                                                                            \
    const unsigned short* la = &lds[(buf) << 14];                              \
    const unsigned short* lb = la + 8192;                                      \
    bf16x8 af[8], bff[4];                                                      \
    _Pragma("unroll")                                                          \
    for (int m = 0; m < 8; ++m)                                                \
      af[m] = *(const bf16x8*)&la[(((wr << 7) + (m << 4) + lrow) << 5) + fsl]; \
    _Pragma("unroll")                                                          \
    for (int n = 0; n < 4; ++n)                                                \
      bff[n] = *(const bf16x8*)&lb[(((wc << 6) + (n << 4) + lrow) << 5) + fsl];\
    __builtin_amdgcn_s_setprio(1);                                             \
    _Pragma("unroll")                                                          \
    for (int m = 0; m < 8; ++m)                                                \
      _Pragma("unroll")                                                        \
      for (int n = 0; n < 4; ++n)                                              \
        acc[m][n] = __builtin_amdgcn_mfma_f32_16x16x32_bf16(                   \
            af[m], bff[n], acc[m][n], 0, 0, 0);                                \
    __builtin_amdgcn_s_setprio(0);                                             \
  }

#define STEP(cb, sbuf, kt)                                                     \
  {                                                                            \
    STAGE(sbuf, kt);                                                           \
    asm volatile("s_waitcnt vmcnt(12)\n\ts_barrier" ::: "memory");             \
    COMPUTE(cb);                                                               \
    asm volatile("s_waitcnt lgkmcnt(0)\n\ts_barrier" ::: "memory");            \
  }

  STAGE(0, 0); STAGE(1, 1); STAGE(2, 2);     // prologue: K-steps 0..2
  for (int I = 0; I < 31; ++I) {             // t = 4I .. 4I+3  (t = 0..123)
    const int t = I << 2;
    STEP(0, 3, t + 3); STEP(1, 0, t + 4); STEP(2, 1, t + 5); STEP(3, 2, t + 6);
  }
  STEP(0, 3, 127);                           // t=124: compute buf0, stage last
  asm volatile("s_waitcnt vmcnt(8)\n\ts_barrier" ::: "memory");   // t=125
  COMPUTE(1);
  asm volatile("s_waitcnt lgkmcnt(0)\n\ts_barrier" ::: "memory");
  asm volatile("s_waitcnt vmcnt(4)\n\ts_barrier" ::: "memory");   // t=126
  COMPUTE(2);
  asm volatile("s_waitcnt lgkmcnt(0)\n\ts_barrier" ::: "memory");
  asm volatile("s_waitcnt vmcnt(0)\n\ts_barrier" ::: "memory");   // t=127
  COMPUTE(3);

  // epilogue: C/D layout col = lane&15, row = (lane>>4)*4 + j  [m89/m91]
  const int ch = lane >> 4;
  float* op = out + (M0 + (size_t)(wr << 7)) * F_OUT + ((size_t)bcol << 8) + (wc << 6);
  #pragma unroll
  for (int m = 0; m < 8; ++m)
    #pragma unroll
    for (int n = 0; n < 4; ++n)
      #pragma unroll
      for (int j = 0; j < 4; ++j)
        op[(size_t)((m << 4) + (ch << 2) + j) * F_OUT + (n << 4) + lrow] = acc[m][n][j];
#undef STAGE
#undef COMPUTE
#undef STEP
}

// ---------------- fallback kernels (small ws) ------------------------------
__global__ __launch_bounds__(256) void scatter_kernel(
    const int* __restrict__ rows, const int* __restrict__ cols,
    const float* __restrict__ wre, const float* __restrict__ wim,
    unsigned short* __restrict__ Wcb) {
  int e = blockIdx.x * 256 + threadIdx.x;
  int r = rows[e];
  int c = cols[e];
  unsigned pk = (unsigned)f2bf(wre[e]) | ((unsigned)f2bf(wim[e]) << 16);
  size_t idx = ((size_t)r << 12) + (size_t)c;
  asm volatile("global_atomic_pk_add_bf16 %0, %1, off"
               :: "v"(Wcb + (idx << 1)), "v"(pk) : "memory");
}
__global__ __launch_bounds__(256) void fold_kernel(
    const unsigned short* __restrict__ Wcb, const float* __restrict__ phase,
    unsigned short* __restrict__ Wb) {
  size_t i8 = ((size_t)blockIdx.x * 256 + threadIdx.x) << 3;
  float cb[4];
  cb[0] = cosf(phase[0]); cb[1] = cosf(phase[1]);
  cb[2] = cosf(phase[2]); cb[3] = cosf(phase[3]);
  const unsigned short* p = Wcb + (i8 << 1);
  u16x8 a = *(const u16x8*)(p);
  u16x8 b = *(const u16x8*)(p + 8);
  float rr[8], ii[8];
  rr[0] = bf2f(a[0]); ii[0] = bf2f(a[1]);
  rr[1] = bf2f(a[2]); ii[1] = bf2f(a[3]);
  rr[2] = bf2f(a[4]); ii[2] = bf2f(a[5]);
  rr[3] = bf2f(a[6]); ii[3] = bf2f(a[7]);
  rr[4] = bf2f(b[0]); ii[4] = bf2f(b[1]);
  rr[5] = bf2f(b[2]); ii[5] = bf2f(b[3]);
  rr[6] = bf2f(b[4]); ii[6] = bf2f(b[5]);
  rr[7] = bf2f(b[6]); ii[7] = bf2f(b[7]);
  #pragma unroll
  for (int bb = 0; bb < 4; ++bb) {
    float c = cb[bb];
    u16x8 v;
    #pragma unroll
    for (int j = 0; j < 8; ++j) v[j] = f2bf(rr[j] + c * ii[j]);
    *(u16x8*)(Wb + ((size_t)bb << 24) + i8) = v;
  }
}
__global__ __launch_bounds__(256) void xconv_kernel(
    const float* __restrict__ x, unsigned short* __restrict__ Xb) {
  size_t i8 = ((size_t)blockIdx.x * 256 + threadIdx.x) << 3;
  f32x4 a = *(const f32x4*)(x + i8);
  f32x4 c = *(const f32x4*)(x + i8 + 4);
  u16x8 v;
  v[0] = f2bf(a[0]); v[1] = f2bf(a[1]); v[2] = f2bf(a[2]); v[3] = f2bf(a[3]);
  v[4] = f2bf(c[0]); v[5] = f2bf(c[1]); v[6] = f2bf(c[2]); v[7] = f2bf(c[3]);
  *(u16x8*)(Xb + i8) = v;
}
__global__ __launch_bounds__(256) void naive_kernel(
    const float* __restrict__ x, const unsigned short* __restrict__ Wcb,
    const float* __restrict__ phase, float* __restrict__ out) {
  int n = blockIdx.x >> 4;
  int r = ((blockIdx.x & 15) << 8) | threadIdx.x;
  float cb = cosf(phase[n >> 11]);
  const float* xp = x + ((size_t)n << 12);
  const unsigned short* wc = Wcb + (((size_t)r << 12) << 1);
  float ar = 0.f, ai = 0.f;
  for (int k = 0; k < K_IN; ++k) {
    float xv = xp[k];
    ar += xv * bf2f(wc[2 * k]);
    ai += xv * bf2f(wc[2 * k + 1]);
  }
  out[((size_t)n << 12) + r] = ar + cb * ai;
}

// ---------------------------------------------------------------------------
extern "C" void kernel_launch(void* const* d_in, const int* in_sizes, int n_in,
                              void* d_out, int out_size, void* d_ws, size_t ws_size,
                              hipStream_t stream) {
  const float* x     = (const float*)d_in[0];
  const int*   rows  = (const int*)d_in[1];
  const int*   cols  = (const int*)d_in[2];
  const float* wre   = (const float*)d_in[3];
  const float* wim   = (const float*)d_in[4];
  const float* phase = (const float*)d_in[5];
  float* out = (float*)d_out;

  const size_t WS_FULL = (size_t)268435456;  // 256MB
  const size_t WS_MAIN = (size_t)201326592;  // 192MB
  if (ws_size >= WS_FULL) {
    // Wb [0,128MB) | Xb [128,192MB) | records [192,~232MB) | cursor @240MB
    unsigned short*     Wb      = (unsigned short*)d_ws;
    unsigned short*     Xb      = (unsigned short*)((char*)d_ws + (size_t)134217728);
    unsigned long long* records = (unsigned long long*)((char*)d_ws + (size_t)201326592);
    unsigned*           cursor  = (unsigned*)((char*)d_ws + (size_t)251658240);
    hipMemsetAsync(cursor, 0, NBUCK * sizeof(unsigned), stream);
    bin_kernel<<<256 + 4096, 1024, 0, stream>>>(rows, cols, wre, wim,
                                                cursor, records, x, Xb);
    assemble_kernel<<<NBUCK, 1024, 0, stream>>>(cursor, records, phase, Wb);
    gemm_kernel<<<512, 512, 0, stream>>>(Xb, Wb, out);
  } else if (ws_size >= WS_MAIN) {
    unsigned short* Wcb = (unsigned short*)d_ws;
    unsigned short* Wb  = (unsigned short*)((char*)d_ws + (size_t)67108864);
    unsigned short* Xb  = (unsigned short*)d_ws;
    hipMemsetAsync(d_ws, 0, (size_t)WELEM * 4, stream);
    scatter_kernel<<<NNZ / 256, 256, 0, stream>>>(rows, cols, wre, wim, Wcb);
    fold_kernel<<<WELEM / 8 / 256, 256, 0, stream>>>(Wcb, phase, Wb);
    xconv_kernel<<<(size_t)NROW * K_IN / 8 / 256, 256, 0, stream>>>(x, Xb);
    gemm_kernel<<<512, 512, 0, stream>>>(Xb, Wb, out);
  } else {
    unsigned short* Wcb = (unsigned short*)d_ws;
    hipMemsetAsync(d_ws, 0, (size_t)WELEM * 4, stream);
    scatter_kernel<<<NNZ / 256, 256, 0, stream>>>(rows, cols, wre, wim, Wcb);
    naive_kernel<<<NROW * 16, 256, 0, stream>>>(x, Wcb, phase, out);
  }
}

// Round 21
// 379.092 us; speedup vs baseline: 1.0813x; 1.0643x over previous
//
#include <hip/hip_runtime.h>

// ---------------------------------------------------------------------------
// ComplexHoloLinear: out[n,r] = sum_k x[n,k] * (Wr[r,k] + cos(phase[b])*Wi[r,k])
// b = n / SEQ.  Wr/Wi dense-assembled from COO (duplicates sum).
//
// Pipeline: memset(4KB) -> bin (256 scatter blocks: LDS bucket-sort,
// reg-cached rows || 4096 xconv blocks) -> assemble (1024 blocks, 64KB LDS,
// 2 row-half passes) -> gemm R21: R14 4-buffer BK=32 deep prefetch with a
// SINGLE barrier per K-step: {vmcnt(8) lgkm(0); barrier; STAGE(t+3);
// COMPUTE(t)}.  Safety ledger: lgkm(0)+barrier block-wide-drains
// COMPUTE(t-1)'s ds_reads before STAGE(t+3) overwrites buf (t-1)&3;
// vmcnt(8) retires buf t's loads (12 outstanding max, oldest 4 = buf t).
// Protected decisions:
//   - launch_bounds(512,2): (512,4) caps VGPR 64 -> acc spill 10x (R17)
//   - 16x16x32 MFMA: 32x32x16 adds 2.5e7 conflicts, no win (R11)
//   - 2-buffer/64KB: occupancy unchanged, loses prefetch depth (R19)
//   - phase-split schedules: 3 faithful attempts regressed (R5/R6/R9)
// ---------------------------------------------------------------------------

#define K_IN   4096
#define F_OUT  4096
#define SEQ    2048
#define NROW   8192            // BATCH * SEQ
#define NNZ    4194304
#define WELEM  16777216        // F_OUT * K_IN
#define NBUCK  1024            // buckets of 4 rows
#define SEGB   5120            // slots/bucket; lambda=4096 -> 16 sigma

typedef float  f32x4  __attribute__((ext_vector_type(4)));
typedef __bf16 bf16x8 __attribute__((ext_vector_type(8)));
typedef unsigned short u16x8 __attribute__((ext_vector_type(8)));

__device__ __forceinline__ unsigned short f2bf(float f) {
  unsigned u = __builtin_bit_cast(unsigned, f);
  u += 0x7fffu + ((u >> 16) & 1u);          // round-to-nearest-even
  return (unsigned short)(u >> 16);
}
__device__ __forceinline__ float bf2f(unsigned short b) {
  return __builtin_bit_cast(float, (unsigned)b << 16);
}

// ---------------- 1. bucket-bin COO (LDS sort) + fused xconv --------------
// record = pk<<32 | bucket<<14 | rlow<<12 | col  (assemble masks &16383).
__global__ __launch_bounds__(1024) void bin_kernel(
    const int* __restrict__ rows, const int* __restrict__ cols,
    const float* __restrict__ wre, const float* __restrict__ wim,
    unsigned* __restrict__ cursor, unsigned long long* __restrict__ records,
    const float* __restrict__ x, unsigned short* __restrict__ Xb) {
  __shared__ unsigned long long sorted[16384];   // 128 KB
  __shared__ unsigned cnt[NBUCK];                // 4 KB (mutable cursor)
  __shared__ unsigned loff[NBUCK];               // 4 KB (pristine excl scan)
  __shared__ unsigned gbase[NBUCK];              // 4 KB (global claim base)
  const int b = blockIdx.x;
  if (b < 256) {
    const int tid = threadIdx.x;
    const int e0 = b << 14;                  // 16384 entries per block
    cnt[tid] = 0u;
    __syncthreads();
    int rcache[16];                          // rows cached in regs (pass2 reuse)
    #pragma unroll
    for (int i = 0; i < 16; ++i) {           // pass 1: count per bucket
      rcache[i] = rows[e0 + (i << 10) + tid];
      atomicAdd(&cnt[((unsigned)rcache[i]) >> 2], 1u);
    }
    __syncthreads();
    const unsigned c0 = cnt[tid];
    gbase[tid] = c0 ? atomicAdd(&cursor[tid], c0) : 0u;
    // inclusive scan of cnt into loff
    loff[tid] = c0;
    __syncthreads();
    #pragma unroll
    for (int d = 1; d < 1024; d <<= 1) {
      const unsigned v = loff[tid];
      const unsigned a = (tid >= d) ? loff[tid - d] : 0u;
      __syncthreads();
      loff[tid] = v + a;
      __syncthreads();
    }
    const unsigned excl = loff[tid] - c0;
    loff[tid] = excl;                        // pristine exclusive offset
    cnt[tid]  = excl;                        // running local cursor
    __syncthreads();
    for (int i = 0; i < 16; ++i) {           // pass 2: LDS bucket-sort
      const int e = e0 + (i << 10) + tid;
      const unsigned r  = (unsigned)rcache[i];
      const unsigned bk = r >> 2;
      const unsigned lr = atomicAdd(&cnt[bk], 1u);
      const unsigned pk = (unsigned)f2bf(wre[e]) | ((unsigned)f2bf(wim[e]) << 16);
      sorted[lr] = ((unsigned long long)pk << 32) |
                   ((unsigned long long)bk << 14) |
                   ((r & 3u) << 12) | (unsigned)cols[e];
    }
    __syncthreads();
    #pragma unroll
    for (int i = 0; i < 16; ++i) {           // streaming write, run-coalesced
      const int idx = (i << 10) + tid;
      const unsigned long long v = sorted[idx];
      const unsigned bk = (unsigned)(v >> 14) & 1023u;
      const unsigned dst = gbase[bk] + ((unsigned)idx - loff[bk]);
      if (dst < SEGB) records[(size_t)bk * SEGB + dst] = v;
    }
  } else {                                   // xconv: 4096 blocks x 8192 elems
    const size_t i8 = (((size_t)(b - 256) << 10) + threadIdx.x) << 3;
    f32x4 a = *(const f32x4*)(x + i8);
    f32x4 c = *(const f32x4*)(x + i8 + 4);
    u16x8 v;
    v[0] = f2bf(a[0]); v[1] = f2bf(a[1]); v[2] = f2bf(a[2]); v[3] = f2bf(a[3]);
    v[4] = f2bf(c[0]); v[5] = f2bf(c[1]); v[6] = f2bf(c[2]); v[7] = f2bf(c[3]);
    *(u16x8*)(Xb + i8) = v;
  }
}

// ---------------- 2. assemble bucket in 2 row-half passes + fold ----------
__global__ __launch_bounds__(1024) void assemble_kernel(
    const unsigned* __restrict__ cursor,
    const unsigned long long* __restrict__ records,
    const float* __restrict__ phase, unsigned short* __restrict__ Wb) {
  __shared__ float accRe[8192];              // 32 KB  (2 rows x 4096 cols)
  __shared__ float accIm[8192];              // 32 KB
  const int bk  = blockIdx.x;
  const int tid = threadIdx.x;
  unsigned cnt = cursor[bk];
  if (cnt > SEGB) cnt = SEGB;
  const unsigned long long* seg = records + (size_t)bk * SEGB;
  float cb[4];
  cb[0] = cosf(phase[0]); cb[1] = cosf(phase[1]);
  cb[2] = cosf(phase[2]); cb[3] = cosf(phase[3]);
  #pragma unroll
  for (int p = 0; p < 2; ++p) {              // row-half p: rows 2p, 2p+1
    #pragma unroll
    for (int i = 0; i < 8; ++i) {
      accRe[(i << 10) + tid] = 0.f;
      accIm[(i << 10) + tid] = 0.f;
    }
    __syncthreads();
    for (unsigned i = tid; i < cnt; i += 1024) {
      const unsigned long long rec = seg[i];
      const unsigned s = (unsigned)rec & 16383u;   // rlow*4096 + col
      if ((int)(s >> 13) == p) {
        const unsigned sh = s & 8191u;
        atomicAdd(&accRe[sh], bf2f((unsigned short)((rec >> 32) & 0xffffu)));
        atomicAdd(&accIm[sh], bf2f((unsigned short)(rec >> 48)));
      }
    }
    __syncthreads();
    #pragma unroll
    for (int it = 0; it < 8; ++it) {
      const int sh = (it << 10) + tid;
      const float re = accRe[sh];
      const float im = accIm[sh];
      const size_t off = ((size_t)bk << 14) + ((size_t)p << 13) + sh;
      #pragma unroll
      for (int bb = 0; bb < 4; ++bb)         // == row*4096 + col
        Wb[((size_t)bb << 24) + off] = f2bf(re + cb[bb] * im);
    }
    __syncthreads();                         // fold reads done before re-zero
  }
}

// ---------------- 3. bf16 GEMM: out = Xb @ Wb[batch]^T --------------------
// 256x256 tile, 512 thr (8 waves 2x4), 16x16x32 MFMA, BK=32, FOUR 32KB LDS
// bufs, 3-iter-deep prefetch.  R21: ONE barrier per K-step:
//   {vmcnt(8) lgkm(0); barrier; STAGE(t+3); COMPUTE(t)}
#define GLOAD_LDS(g, l)                                                        \
  __builtin_amdgcn_global_load_lds(                                            \
      (const __attribute__((address_space(1))) unsigned int*)(g),              \
      (__attribute__((address_space(3))) unsigned int*)(l), 16, 0, 0)

__global__ __launch_bounds__(512, 2) void gemm_kernel(
    const unsigned short* __restrict__ Xb,   // [8192][4096] bf16 bits
    const unsigned short* __restrict__ Wb,   // [4][4096][4096] bf16 bits
    float* __restrict__ out) {               // [8192][4096] f32
  __shared__ unsigned short lds[65536];      // 128KB: 4 bufs x [A|B][256][32]

  const int tid  = threadIdx.x;
  const int wid  = tid >> 6;                 // 0..7
  const int lane = tid & 63;
  const int wr   = wid >> 2;                 // wave row 0..1 (128 rows each)
  const int wc   = wid & 3;                  // wave col 0..3 (64 cols each)

  const int bid  = blockIdx.x;               // 0..511
  const int swz  = ((bid & 7) << 6) | (bid >> 3);  // xcd*64 + idx (512%8==0)
  const int brow = swz >> 4;                 // 0..31
  const int bcol = swz & 15;                 // 0..15
  const size_t M0 = (size_t)brow << 8;       // *256
  const int batch = brow >> 3;               // 2048 rows/batch / 256
  const unsigned short* Ap = Xb + M0 * K_IN;
  const unsigned short* Bp = Wb + ((size_t)batch << 24) + (((size_t)bcol << 8) * K_IN);

  // staging geometry: per round, wave covers 16 rows x 4 slots of 16B
  const int srow4 = lane >> 2;               // row within 16-row chunk
  const int gsl   = (((lane & 3) ^ ((lane >> 2) & 3) ^ ((lane >> 4) & 3)) << 3);
  // fragment geometry (16x16x32, K=32 = full buf)
  const int lrow = lane & 15;
  const int sb   = lane >> 4;                // k-slot 0..3
  const int fsl  = ((sb ^ (lrow & 3) ^ ((lrow >> 2) & 3)) << 3);

  f32x4 acc[8][4] = {};

#define STAGE(buf, kt)                                                         \
  {                                                                            \
    _Pragma("unroll")                                                          \
    for (int l = 0; l < 2; ++l) {                                              \
      const int rb = (l << 7) + (wid << 4);                                    \
      GLOAD_LDS(Ap + (size_t)(rb + srow4) * K_IN + (size_t)(((kt) << 5) + gsl),\
                &lds[((buf) << 14) + (rb << 5)]);                              \
    }                                                                          \
    _Pragma("unroll")                                                          \
    for (int l = 0; l < 2; ++l) {                                              \
      const int rb = (l << 7) + (wid << 4);                                    \
      GLOAD_LDS(Bp + (size_t)(rb + srow4) * K_IN + (size_t)(((kt) << 5) + gsl),\
                &lds[((buf) << 14) + 8192 + (rb << 5)]);                       \
    }                                                                          \
  }

#define COMPUTE(buf)                                                           \
  {                                                                            \
    const unsigned short* la = &lds[(buf) << 14];                              \
    const unsigned short* lb = la + 8192;                                      \
    bf16x8 af[8], bff[4];                                                      \
    _Pragma("unroll")                                                          \
    for (int m = 0; m < 8; ++m)                                                \
      af[m] = *(const bf16x8*)&la[(((wr << 7) + (m << 4) + lrow) << 5) + fsl]; \
    _Pragma("unroll")                                                          \
    for (int n = 0; n < 4; ++n)                                                \
      bff[n] = *(const bf16x8*)&lb[(((wc << 6) + (n << 4) + lrow) << 5) + fsl];\
    __builtin_amdgcn_s_setprio(1);                                             \
    _Pragma("unroll")                                                          \
    for (int m = 0; m < 8; ++m)                                                \
      _Pragma("unroll")                                                        \
      for (int n = 0; n < 4; ++n)                                              \
        acc[m][n] = __builtin_amdgcn_mfma_f32_16x16x32_bf16(                   \
            af[m], bff[n], acc[m][n], 0, 0, 0);                                \
    __builtin_amdgcn_s_setprio(0);                                             \
  }

// one K-step: drain own ds-queue + oldest vm loads, block-sync, stage, compute
#define STEP(cb, sbuf, kt)                                                     \
  {                                                                            \
    asm volatile("s_waitcnt vmcnt(8) lgkmcnt(0)" ::: "memory");                \
    __builtin_amdgcn_s_barrier();                                              \
    STAGE(sbuf, kt);                                                           \
    COMPUTE(cb);                                                               \
  }

  STAGE(0, 0); STAGE(1, 1); STAGE(2, 2);     // prologue: K-steps 0..2
  for (int I = 0; I < 31; ++I) {             // t = 4I .. 4I+3  (t = 0..123)
    const int t = I << 2;
    STEP(0, 3, t + 3); STEP(1, 0, t + 4); STEP(2, 1, t + 5); STEP(3, 2, t + 6);
  }
  STEP(0, 3, 127);                           // t=124: compute buf0, stage k127
  asm volatile("s_waitcnt vmcnt(8) lgkmcnt(0)" ::: "memory");   // t=125
  __builtin_amdgcn_s_barrier();
  COMPUTE(1);
  asm volatile("s_waitcnt vmcnt(4) lgkmcnt(0)" ::: "memory");   // t=126
  __builtin_amdgcn_s_barrier();
  COMPUTE(2);
  asm volatile("s_waitcnt vmcnt(0) lgkmcnt(0)" ::: "memory");   // t=127
  __builtin_amdgcn_s_barrier();
  COMPUTE(3);

  // epilogue: C/D layout col = lane&15, row = (lane>>4)*4 + j  [m89/m91]
  const int ch = lane >> 4;
  float* op = out + (M0 + (size_t)(wr << 7)) * F_OUT + ((size_t)bcol << 8) + (wc << 6);
  #pragma unroll
  for (int m = 0; m < 8; ++m)
    #pragma unroll
    for (int n = 0; n < 4; ++n)
      #pragma unroll
      for (int j = 0; j < 4; ++j)
        op[(size_t)((m << 4) + (ch << 2) + j) * F_OUT + (n << 4) + lrow] = acc[m][n][j];
#undef STAGE
#undef COMPUTE
#undef STEP
}

// ---------------- fallback kernels (small ws) ------------------------------
__global__ __launch_bounds__(256) void scatter_kernel(
    const int* __restrict__ rows, const int* __restrict__ cols,
    const float* __restrict__ wre, const float* __restrict__ wim,
    unsigned short* __restrict__ Wcb) {
  int e = blockIdx.x * 256 + threadIdx.x;
  int r = rows[e];
  int c = cols[e];
  unsigned pk = (unsigned)f2bf(wre[e]) | ((unsigned)f2bf(wim[e]) << 16);
  size_t idx = ((size_t)r << 12) + (size_t)c;
  asm volatile("global_atomic_pk_add_bf16 %0, %1, off"
               :: "v"(Wcb + (idx << 1)), "v"(pk) : "memory");
}
__global__ __launch_bounds__(256) void fold_kernel(
    const unsigned short* __restrict__ Wcb, const float* __restrict__ phase,
    unsigned short* __restrict__ Wb) {
  size_t i8 = ((size_t)blockIdx.x * 256 + threadIdx.x) << 3;
  float cb[4];
  cb[0] = cosf(phase[0]); cb[1] = cosf(phase[1]);
  cb[2] = cosf(phase[2]); cb[3] = cosf(phase[3]);
  const unsigned short* p = Wcb + (i8 << 1);
  u16x8 a = *(const u16x8*)(p);
  u16x8 b = *(const u16x8*)(p + 8);
  float rr[8], ii[8];
  rr[0] = bf2f(a[0]); ii[0] = bf2f(a[1]);
  rr[1] = bf2f(a[2]); ii[1] = bf2f(a[3]);
  rr[2] = bf2f(a[4]); ii[2] = bf2f(a[5]);
  rr[3] = bf2f(a[6]); ii[3] = bf2f(a[7]);
  rr[4] = bf2f(b[0]); ii[4] = bf2f(b[1]);
  rr[5] = bf2f(b[2]); ii[5] = bf2f(b[3]);
  rr[6] = bf2f(b[4]); ii[6] = bf2f(b[5]);
  rr[7] = bf2f(b[6]); ii[7] = bf2f(b[7]);
  #pragma unroll
  for (int bb = 0; bb < 4; ++bb) {
    float c = cb[bb];
    u16x8 v;
    #pragma unroll
    for (int j = 0; j < 8; ++j) v[j] = f2bf(rr[j] + c * ii[j]);
    *(u16x8*)(Wb + ((size_t)bb << 24) + i8) = v;
  }
}
__global__ __launch_bounds__(256) void xconv_kernel(
    const float* __restrict__ x, unsigned short* __restrict__ Xb) {
  size_t i8 = ((size_t)blockIdx.x * 256 + threadIdx.x) << 3;
  f32x4 a = *(const f32x4*)(x + i8);
  f32x4 c = *(const f32x4*)(x + i8 + 4);
  u16x8 v;
  v[0] = f2bf(a[0]); v[1] = f2bf(a[1]); v[2] = f2bf(a[2]); v[3] = f2bf(a[3]);
  v[4] = f2bf(c[0]); v[5] = f2bf(c[1]); v[6] = f2bf(c[2]); v[7] = f2bf(c[3]);
  *(u16x8*)(Xb + i8) = v;
}
__global__ __launch_bounds__(256) void naive_kernel(
    const float* __restrict__ x, const unsigned short* __restrict__ Wcb,
    const float* __restrict__ phase, float* __restrict__ out) {
  int n = blockIdx.x >> 4;
  int r = ((blockIdx.x & 15) << 8) | threadIdx.x;
  float cb = cosf(phase[n >> 11]);
  const float* xp = x + ((size_t)n << 12);
  const unsigned short* wc = Wcb + (((size_t)r << 12) << 1);
  float ar = 0.f, ai = 0.f;
  for (int k = 0; k < K_IN; ++k) {
    float xv = xp[k];
    ar += xv * bf2f(wc[2 * k]);
    ai += xv * bf2f(wc[2 * k + 1]);
  }
  out[((size_t)n << 12) + r] = ar + cb * ai;
}

// ---------------------------------------------------------------------------
extern "C" void kernel_launch(void* const* d_in, const int* in_sizes, int n_in,
                              void* d_out, int out_size, void* d_ws, size_t ws_size,
                              hipStream_t stream) {
  const float* x     = (const float*)d_in[0];
  const int*   rows  = (const int*)d_in[1];
  const int*   cols  = (const int*)d_in[2];
  const float* wre   = (const float*)d_in[3];
  const float* wim   = (const float*)d_in[4];
  const float* phase = (const float*)d_in[5];
  float* out = (float*)d_out;

  const size_t WS_FULL = (size_t)268435456;  // 256MB
  const size_t WS_MAIN = (size_t)201326592;  // 192MB
  if (ws_size >= WS_FULL) {
    // Wb [0,128MB) | Xb [128,192MB) | records [192,~232MB) | cursor @240MB
    unsigned short*     Wb      = (unsigned short*)d_ws;
    unsigned short*     Xb      = (unsigned short*)((char*)d_ws + (size_t)134217728);
    unsigned long long* records = (unsigned long long*)((char*)d_ws + (size_t)201326592);
    unsigned*           cursor  = (unsigned*)((char*)d_ws + (size_t)251658240);
    hipMemsetAsync(cursor, 0, NBUCK * sizeof(unsigned), stream);
    bin_kernel<<<256 + 4096, 1024, 0, stream>>>(rows, cols, wre, wim,
                                                cursor, records, x, Xb);
    assemble_kernel<<<NBUCK, 1024, 0, stream>>>(cursor, records, phase, Wb);
    gemm_kernel<<<512, 512, 0, stream>>>(Xb, Wb, out);
  } else if (ws_size >= WS_MAIN) {
    unsigned short* Wcb = (unsigned short*)d_ws;
    unsigned short* Wb  = (unsigned short*)((char*)d_ws + (size_t)67108864);
    unsigned short* Xb  = (unsigned short*)d_ws;
    hipMemsetAsync(d_ws, 0, (size_t)WELEM * 4, stream);
    scatter_kernel<<<NNZ / 256, 256, 0, stream>>>(rows, cols, wre, wim, Wcb);
    fold_kernel<<<WELEM / 8 / 256, 256, 0, stream>>>(Wcb, phase, Wb);
    xconv_kernel<<<(size_t)NROW * K_IN / 8 / 256, 256, 0, stream>>>(x, Xb);
    gemm_kernel<<<512, 512, 0, stream>>>(Xb, Wb, out);
  } else {
    unsigned short* Wcb = (unsigned short*)d_ws;
    hipMemsetAsync(d_ws, 0, (size_t)WELEM * 4, stream);
    scatter_kernel<<<NNZ / 256, 256, 0, stream>>>(rows, cols, wre, wim, Wcb);
    naive_kernel<<<NROW * 16, 256, 0, stream>>>(x, Wcb, phase, out);
  }
}

// Round 23
// 377.903 us; speedup vs baseline: 1.0847x; 1.0031x over previous
//
#include <hip/hip_runtime.h>

// ---------------------------------------------------------------------------
// ComplexHoloLinear: out[n,r] = sum_k x[n,k] * (Wr[r,k] + cos(phase[b])*Wi[r,k])
// b = n / SEQ.  Wr/Wi dense-assembled from COO (duplicates sum).
//
// FINAL pipeline (R21, 379.1us): memset(4KB) -> bin (256 scatter blocks:
// LDS bucket-sort, reg-cached rows || 4096 xconv blocks) -> assemble
// (1024 blocks, 64KB LDS, 2 row-half passes) -> gemm (256x256, BK=32,
// FOUR 32KB LDS bufs, 3-iter-deep prefetch, ONE barrier per K-step:
//   {vmcnt(8) lgkm(0); barrier; STAGE(t+3); COMPUTE(t)} ).
// This is the UNIQUE correct single-barrier order: vmcnt must precede the
// barrier (vmcnt is per-wave; cross-wave LDS visibility of staged data
// requires every wave to retire its buf-t loads BEFORE the sync). R22's
// issue-before-wait variant raced and failed post-timing validation.
// Protected decisions:
//   - launch_bounds(512,2): (512,4) caps VGPR 64 -> acc spill 10x (R17)
//   - 16x16x32 MFMA: 32x32x16 adds 2.5e7 conflicts, no win (R11)
//   - 2-buffer/64KB: occupancy unchanged, loses prefetch depth (R19)
//   - phase-split schedules: 3 faithful attempts regressed (R5/R6/R9)
//   - lgkm(0) in the pre-barrier wait: DS-drain before buffer reuse (R10)
// ---------------------------------------------------------------------------

#define K_IN   4096
#define F_OUT  4096
#define SEQ    2048
#define NROW   8192            // BATCH * SEQ
#define NNZ    4194304
#define WELEM  16777216        // F_OUT * K_IN
#define NBUCK  1024            // buckets of 4 rows
#define SEGB   5120            // slots/bucket; lambda=4096 -> 16 sigma

typedef float  f32x4  __attribute__((ext_vector_type(4)));
typedef __bf16 bf16x8 __attribute__((ext_vector_type(8)));
typedef unsigned short u16x8 __attribute__((ext_vector_type(8)));

__device__ __forceinline__ unsigned short f2bf(float f) {
  unsigned u = __builtin_bit_cast(unsigned, f);
  u += 0x7fffu + ((u >> 16) & 1u);          // round-to-nearest-even
  return (unsigned short)(u >> 16);
}
__device__ __forceinline__ float bf2f(unsigned short b) {
  return __builtin_bit_cast(float, (unsigned)b << 16);
}

// ---------------- 1. bucket-bin COO (LDS sort) + fused xconv --------------
// record = pk<<32 | bucket<<14 | rlow<<12 | col  (assemble masks &16383).
__global__ __launch_bounds__(1024) void bin_kernel(
    const int* __restrict__ rows, const int* __restrict__ cols,
    const float* __restrict__ wre, const float* __restrict__ wim,
    unsigned* __restrict__ cursor, unsigned long long* __restrict__ records,
    const float* __restrict__ x, unsigned short* __restrict__ Xb) {
  __shared__ unsigned long long sorted[16384];   // 128 KB
  __shared__ unsigned cnt[NBUCK];                // 4 KB (mutable cursor)
  __shared__ unsigned loff[NBUCK];               // 4 KB (pristine excl scan)
  __shared__ unsigned gbase[NBUCK];              // 4 KB (global claim base)
  const int b = blockIdx.x;
  if (b < 256) {
    const int tid = threadIdx.x;
    const int e0 = b << 14;                  // 16384 entries per block
    cnt[tid] = 0u;
    __syncthreads();
    int rcache[16];                          // rows cached in regs (pass2 reuse)
    #pragma unroll
    for (int i = 0; i < 16; ++i) {           // pass 1: count per bucket
      rcache[i] = rows[e0 + (i << 10) + tid];
      atomicAdd(&cnt[((unsigned)rcache[i]) >> 2], 1u);
    }
    __syncthreads();
    const unsigned c0 = cnt[tid];
    gbase[tid] = c0 ? atomicAdd(&cursor[tid], c0) : 0u;
    // inclusive scan of cnt into loff
    loff[tid] = c0;
    __syncthreads();
    #pragma unroll
    for (int d = 1; d < 1024; d <<= 1) {
      const unsigned v = loff[tid];
      const unsigned a = (tid >= d) ? loff[tid - d] : 0u;
      __syncthreads();
      loff[tid] = v + a;
      __syncthreads();
    }
    const unsigned excl = loff[tid] - c0;
    loff[tid] = excl;                        // pristine exclusive offset
    cnt[tid]  = excl;                        // running local cursor
    __syncthreads();
    for (int i = 0; i < 16; ++i) {           // pass 2: LDS bucket-sort
      const int e = e0 + (i << 10) + tid;
      const unsigned r  = (unsigned)rcache[i];
      const unsigned bk = r >> 2;
      const unsigned lr = atomicAdd(&cnt[bk], 1u);
      const unsigned pk = (unsigned)f2bf(wre[e]) | ((unsigned)f2bf(wim[e]) << 16);
      sorted[lr] = ((unsigned long long)pk << 32) |
                   ((unsigned long long)bk << 14) |
                   ((r & 3u) << 12) | (unsigned)cols[e];
    }
    __syncthreads();
    #pragma unroll
    for (int i = 0; i < 16; ++i) {           // streaming write, run-coalesced
      const int idx = (i << 10) + tid;
      const unsigned long long v = sorted[idx];
      const unsigned bk = (unsigned)(v >> 14) & 1023u;
      const unsigned dst = gbase[bk] + ((unsigned)idx - loff[bk]);
      if (dst < SEGB) records[(size_t)bk * SEGB + dst] = v;
    }
  } else {                                   // xconv: 4096 blocks x 8192 elems
    const size_t i8 = (((size_t)(b - 256) << 10) + threadIdx.x) << 3;
    f32x4 a = *(const f32x4*)(x + i8);
    f32x4 c = *(const f32x4*)(x + i8 + 4);
    u16x8 v;
    v[0] = f2bf(a[0]); v[1] = f2bf(a[1]); v[2] = f2bf(a[2]); v[3] = f2bf(a[3]);
    v[4] = f2bf(c[0]); v[5] = f2bf(c[1]); v[6] = f2bf(c[2]); v[7] = f2bf(c[3]);
    *(u16x8*)(Xb + i8) = v;
  }
}

// ---------------- 2. assemble bucket in 2 row-half passes + fold ----------
__global__ __launch_bounds__(1024) void assemble_kernel(
    const unsigned* __restrict__ cursor,
    const unsigned long long* __restrict__ records,
    const float* __restrict__ phase, unsigned short* __restrict__ Wb) {
  __shared__ float accRe[8192];              // 32 KB  (2 rows x 4096 cols)
  __shared__ float accIm[8192];              // 32 KB
  const int bk  = blockIdx.x;
  const int tid = threadIdx.x;
  unsigned cnt = cursor[bk];
  if (cnt > SEGB) cnt = SEGB;
  const unsigned long long* seg = records + (size_t)bk * SEGB;
  float cb[4];
  cb[0] = cosf(phase[0]); cb[1] = cosf(phase[1]);
  cb[2] = cosf(phase[2]); cb[3] = cosf(phase[3]);
  #pragma unroll
  for (int p = 0; p < 2; ++p) {              // row-half p: rows 2p, 2p+1
    #pragma unroll
    for (int i = 0; i < 8; ++i) {
      accRe[(i << 10) + tid] = 0.f;
      accIm[(i << 10) + tid] = 0.f;
    }
    __syncthreads();
    for (unsigned i = tid; i < cnt; i += 1024) {
      const unsigned long long rec = seg[i];
      const unsigned s = (unsigned)rec & 16383u;   // rlow*4096 + col
      if ((int)(s >> 13) == p) {
        const unsigned sh = s & 8191u;
        atomicAdd(&accRe[sh], bf2f((unsigned short)((rec >> 32) & 0xffffu)));
        atomicAdd(&accIm[sh], bf2f((unsigned short)(rec >> 48)));
      }
    }
    __syncthreads();
    #pragma unroll
    for (int it = 0; it < 8; ++it) {
      const int sh = (it << 10) + tid;
      const float re = accRe[sh];
      const float im = accIm[sh];
      const size_t off = ((size_t)bk << 14) + ((size_t)p << 13) + sh;
      #pragma unroll
      for (int bb = 0; bb < 4; ++bb)         // == row*4096 + col
        Wb[((size_t)bb << 24) + off] = f2bf(re + cb[bb] * im);
    }
    __syncthreads();                         // fold reads done before re-zero
  }
}

// ---------------- 3. bf16 GEMM: out = Xb @ Wb[batch]^T --------------------
// 256x256 tile, 512 thr (8 waves 2x4), 16x16x32 MFMA, BK=32, FOUR 32KB LDS
// bufs, 3-iter-deep prefetch.  ONE barrier per K-step:
//   {vmcnt(8) lgkm(0); barrier; STAGE(t+3); COMPUTE(t)}
#define GLOAD_LDS(g, l)                                                        \
  __builtin_amdgcn_global_load_lds(                                            \
      (const __attribute__((address_space(1))) unsigned int*)(g),              \
      (__attribute__((address_space(3))) unsigned int*)(l), 16, 0, 0)

__global__ __launch_bounds__(512, 2) void gemm_kernel(
    const unsigned short* __restrict__ Xb,   // [8192][4096] bf16 bits
    const unsigned short* __restrict__ Wb,   // [4][4096][4096] bf16 bits
    float* __restrict__ out) {               // [8192][4096] f32
  __shared__ unsigned short lds[65536];      // 128KB: 4 bufs x [A|B][256][32]

  const int tid  = threadIdx.x;
  const int wid  = tid >> 6;                 // 0..7
  const int lane = tid & 63;
  const int wr   = wid >> 2;                 // wave row 0..1 (128 rows each)
  const int wc   = wid & 3;                  // wave col 0..3 (64 cols each)

  const int bid  = blockIdx.x;               // 0..511
  const int swz  = ((bid & 7) << 6) | (bid >> 3);  // xcd*64 + idx (512%8==0)
  const int brow = swz >> 4;                 // 0..31
  const int bcol = swz & 15;                 // 0..15
  const size_t M0 = (size_t)brow << 8;       // *256
  const int batch = brow >> 3;               // 2048 rows/batch / 256
  const unsigned short* Ap = Xb + M0 * K_IN;
  const unsigned short* Bp = Wb + ((size_t)batch << 24) + (((size_t)bcol << 8) * K_IN);

  // staging geometry: per round, wave covers 16 rows x 4 slots of 16B
  const int srow4 = lane >> 2;               // row within 16-row chunk
  const int gsl   = (((lane & 3) ^ ((lane >> 2) & 3) ^ ((lane >> 4) & 3)) << 3);
  // fragment geometry (16x16x32, K=32 = full buf)
  const int lrow = lane & 15;
  const int sb   = lane >> 4;                // k-slot 0..3
  const int fsl  = ((sb ^ (lrow & 3) ^ ((lrow >> 2) & 3)) << 3);

  f32x4 acc[8][4] = {};

#define STAGE(buf, kt)                                                         \
  {                                                                            \
    _Pragma("unroll")                                                          \
    for (int l = 0; l < 2; ++l) {                                              \
      const int rb = (l << 7) + (wid << 4);                                    \
      GLOAD_LDS(Ap + (size_t)(rb + srow4) * K_IN + (size_t)(((kt) << 5) + gsl),\
                &lds[((buf) << 14) + (rb << 5)]);                              \
    }                                                                          \
    _Pragma("unroll")                                                          \
    for (int l = 0; l < 2; ++l) {                                              \
      const int rb = (l << 7) + (wid << 4);                                    \
      GLOAD_LDS(Bp + (size_t)(rb + srow4) * K_IN + (size_t)(((kt) << 5) + gsl),\
                &lds[((buf) << 14) + 8192 + (rb << 5)]);                       \
    }                                                                          \
  }

#define COMPUTE(buf)                                                           \
  {                                                                            \
    const unsigned short* la = &lds[(buf) << 14];                              \
    const unsigned short* lb = la + 8192;                                      \
    bf16x8 af[8], bff[4];                                                      \
    _Pragma("unroll")                                                          \
    for (int m = 0; m < 8; ++m)                                                \
      af[m] = *(const bf16x8*)&la[(((wr << 7) + (m << 4) + lrow) << 5) + fsl]; \
    _Pragma("unroll")                                                          \
    for (int n = 0; n < 4; ++n)                                                \
      bff[n] = *(const bf16x8*)&lb[(((wc << 6) + (n << 4) + lrow) << 5) + fsl];\
    __builtin_amdgcn_s_setprio(1);                                             \
    _Pragma("unroll")                                                          \
    for (int m = 0; m < 8; ++m)                                                \
      _Pragma("unroll")                                                        \
      for (int n = 0; n < 4; ++n)                                              \
        acc[m][n] = __builtin_amdgcn_mfma_f32_16x16x32_bf16(                   \
            af[m], bff[n], acc[m][n], 0, 0, 0);                                \
    __builtin_amdgcn_s_setprio(0);                                             \
  }

// one K-step: drain own ds-queue + oldest vm loads, block-sync, stage, compute
#define STEP(cb, sbuf, kt)                                                     \
  {                                                                            \
    asm volatile("s_waitcnt vmcnt(8) lgkmcnt(0)" ::: "memory");                \
    __builtin_amdgcn_s_barrier();                                              \
    STAGE(sbuf, kt);                                                           \
    COMPUTE(cb);                                                               \
  }

  STAGE(0, 0); STAGE(1, 1); STAGE(2, 2);     // prologue: K-steps 0..2
  for (int I = 0; I < 31; ++I) {             // t = 4I .. 4I+3  (t = 0..123)
    const int t = I << 2;
    STEP(0, 3, t + 3); STEP(1, 0, t + 4); STEP(2, 1, t + 5); STEP(3, 2, t + 6);
  }
  STEP(0, 3, 127);                           // t=124: compute buf0, stage k127
  asm volatile("s_waitcnt vmcnt(8) lgkmcnt(0)" ::: "memory");   // t=125
  __builtin_amdgcn_s_barrier();
  COMPUTE(1);
  asm volatile("s_waitcnt vmcnt(4) lgkmcnt(0)" ::: "memory");   // t=126
  __builtin_amdgcn_s_barrier();
  COMPUTE(2);
  asm volatile("s_waitcnt vmcnt(0) lgkmcnt(0)" ::: "memory");   // t=127
  __builtin_amdgcn_s_barrier();
  COMPUTE(3);

  // epilogue: C/D layout col = lane&15, row = (lane>>4)*4 + j  [m89/m91]
  const int ch = lane >> 4;
  float* op = out + (M0 + (size_t)(wr << 7)) * F_OUT + ((size_t)bcol << 8) + (wc << 6);
  #pragma unroll
  for (int m = 0; m < 8; ++m)
    #pragma unroll
    for (int n = 0; n < 4; ++n)
      #pragma unroll
      for (int j = 0; j < 4; ++j)
        op[(size_t)((m << 4) + (ch << 2) + j) * F_OUT + (n << 4) + lrow] = acc[m][n][j];
#undef STAGE
#undef COMPUTE
#undef STEP
}

// ---------------- fallback kernels (small ws) ------------------------------
__global__ __launch_bounds__(256) void scatter_kernel(
    const int* __restrict__ rows, const int* __restrict__ cols,
    const float* __restrict__ wre, const float* __restrict__ wim,
    unsigned short* __restrict__ Wcb) {
  int e = blockIdx.x * 256 + threadIdx.x;
  int r = rows[e];
  int c = cols[e];
  unsigned pk = (unsigned)f2bf(wre[e]) | ((unsigned)f2bf(wim[e]) << 16);
  size_t idx = ((size_t)r << 12) + (size_t)c;
  asm volatile("global_atomic_pk_add_bf16 %0, %1, off"
               :: "v"(Wcb + (idx << 1)), "v"(pk) : "memory");
}
__global__ __launch_bounds__(256) void fold_kernel(
    const unsigned short* __restrict__ Wcb, const float* __restrict__ phase,
    unsigned short* __restrict__ Wb) {
  size_t i8 = ((size_t)blockIdx.x * 256 + threadIdx.x) << 3;
  float cb[4];
  cb[0] = cosf(phase[0]); cb[1] = cosf(phase[1]);
  cb[2] = cosf(phase[2]); cb[3] = cosf(phase[3]);
  const unsigned short* p = Wcb + (i8 << 1);
  u16x8 a = *(const u16x8*)(p);
  u16x8 b = *(const u16x8*)(p + 8);
  float rr[8], ii[8];
  rr[0] = bf2f(a[0]); ii[0] = bf2f(a[1]);
  rr[1] = bf2f(a[2]); ii[1] = bf2f(a[3]);
  rr[2] = bf2f(a[4]); ii[2] = bf2f(a[5]);
  rr[3] = bf2f(a[6]); ii[3] = bf2f(a[7]);
  rr[4] = bf2f(b[0]); ii[4] = bf2f(b[1]);
  rr[5] = bf2f(b[2]); ii[5] = bf2f(b[3]);
  rr[6] = bf2f(b[4]); ii[6] = bf2f(b[5]);
  rr[7] = bf2f(b[6]); ii[7] = bf2f(b[7]);
  #pragma unroll
  for (int bb = 0; bb < 4; ++bb) {
    float c = cb[bb];
    u16x8 v;
    #pragma unroll
    for (int j = 0; j < 8; ++j) v[j] = f2bf(rr[j] + c * ii[j]);
    *(u16x8*)(Wb + ((size_t)bb << 24) + i8) = v;
  }
}
__global__ __launch_bounds__(256) void xconv_kernel(
    const float* __restrict__ x, unsigned short* __restrict__ Xb) {
  size_t i8 = ((size_t)blockIdx.x * 256 + threadIdx.x) << 3;
  f32x4 a = *(const f32x4*)(x + i8);
  f32x4 c = *(const f32x4*)(x + i8 + 4);
  u16x8 v;
  v[0] = f2bf(a[0]); v[1] = f2bf(a[1]); v[2] = f2bf(a[2]); v[3] = f2bf(a[3]);
  v[4] = f2bf(c[0]); v[5] = f2bf(c[1]); v[6] = f2bf(c[2]); v[7] = f2bf(c[3]);
  *(u16x8*)(Xb + i8) = v;
}
__global__ __launch_bounds__(256) void naive_kernel(
    const float* __restrict__ x, const unsigned short* __restrict__ Wcb,
    const float* __restrict__ phase, float* __restrict__ out) {
  int n = blockIdx.x >> 4;
  int r = ((blockIdx.x & 15) << 8) | threadIdx.x;
  float cb = cosf(phase[n >> 11]);
  const float* xp = x + ((size_t)n << 12);
  const unsigned short* wc = Wcb + (((size_t)r << 12) << 1);
  float ar = 0.f, ai = 0.f;
  for (int k = 0; k < K_IN; ++k) {
    float xv = xp[k];
    ar += xv * bf2f(wc[2 * k]);
    ai += xv * bf2f(wc[2 * k + 1]);
  }
  out[((size_t)n << 12) + r] = ar + cb * ai;
}

// ---------------------------------------------------------------------------
extern "C" void kernel_launch(void* const* d_in, const int* in_sizes, int n_in,
                              void* d_out, int out_size, void* d_ws, size_t ws_size,
                              hipStream_t stream) {
  const float* x     = (const float*)d_in[0];
  const int*   rows  = (const int*)d_in[1];
  const int*   cols  = (const int*)d_in[2];
  const float* wre   = (const float*)d_in[3];
  const float* wim   = (const float*)d_in[4];
  const float* phase = (const float*)d_in[5];
  float* out = (float*)d_out;

  const size_t WS_FULL = (size_t)268435456;  // 256MB
  const size_t WS_MAIN = (size_t)201326592;  // 192MB
  if (ws_size >= WS_FULL) {
    // Wb [0,128MB) | Xb [128,192MB) | records [192,~232MB) | cursor @240MB
    unsigned short*     Wb      = (unsigned short*)d_ws;
    unsigned short*     Xb      = (unsigned short*)((char*)d_ws + (size_t)134217728);
    unsigned long long* records = (unsigned long long*)((char*)d_ws + (size_t)201326592);
    unsigned*           cursor  = (unsigned*)((char*)d_ws + (size_t)251658240);
    hipMemsetAsync(cursor, 0, NBUCK * sizeof(unsigned), stream);
    bin_kernel<<<256 + 4096, 1024, 0, stream>>>(rows, cols, wre, wim,
                                                cursor, records, x, Xb);
    assemble_kernel<<<NBUCK, 1024, 0, stream>>>(cursor, records, phase, Wb);
    gemm_kernel<<<512, 512, 0, stream>>>(Xb, Wb, out);
  } else if (ws_size >= WS_MAIN) {
    unsigned short* Wcb = (unsigned short*)d_ws;
    unsigned short* Wb  = (unsigned short*)((char*)d_ws + (size_t)67108864);
    unsigned short* Xb  = (unsigned short*)d_ws;
    hipMemsetAsync(d_ws, 0, (size_t)WELEM * 4, stream);
    scatter_kernel<<<NNZ / 256, 256, 0, stream>>>(rows, cols, wre, wim, Wcb);
    fold_kernel<<<WELEM / 8 / 256, 256, 0, stream>>>(Wcb, phase, Wb);
    xconv_kernel<<<(size_t)NROW * K_IN / 8 / 256, 256, 0, stream>>>(x, Xb);
    gemm_kernel<<<512, 512, 0, stream>>>(Xb, Wb, out);
  } else {
    unsigned short* Wcb = (unsigned short*)d_ws;
    hipMemsetAsync(d_ws, 0, (size_t)WELEM * 4, stream);
    scatter_kernel<<<NNZ / 256, 256, 0, stream>>>(rows, cols, wre, wim, Wcb);
    naive_kernel<<<NROW * 16, 256, 0, stream>>>(x, Wcb, phase, out);
  }
}